// Round 2
// baseline (1308.532 us; speedup 1.0000x reference)
//
#include <hip/hip_runtime.h>

typedef __bf16 bf16x8 __attribute__((ext_vector_type(8)));
typedef float f32x4 __attribute__((ext_vector_type(4)));

#define B_ 2
#define S_ 2048
#define D_ 4096
#define H_ 32
#define KV_ 8
#define G_ 4
#define HD_ 128
#define P_ 1024
#define T_ 3072

__device__ inline bf16x8 cvt8(const float4 a, const float4 b) {
  bf16x8 r;
  r[0] = (__bf16)a.x; r[1] = (__bf16)a.y; r[2] = (__bf16)a.z; r[3] = (__bf16)a.w;
  r[4] = (__bf16)b.x; r[5] = (__bf16)b.y; r[6] = (__bf16)b.z; r[7] = (__bf16)b.w;
  return r;
}

// ---------------- f32 -> bf16 elementwise convert (8 elems/thread) ----------
__global__ __launch_bounds__(256) void cvt_f32_bf16(const float* __restrict__ in,
                                                    __bf16* __restrict__ out) {
  const long i = ((long)blockIdx.x * 256 + threadIdx.x) * 8;
  float4 a = *(const float4*)(in + i);
  float4 b = *(const float4*)(in + i + 4);
  *(bf16x8*)(out + i) = cvt8(a, b);
}

// ------------- transpose: out[c][r] = bf16(in[r][c]), in f32 R x C ----------
__global__ __launch_bounds__(256) void transpose2d(const float* __restrict__ in,
                                                   __bf16* __restrict__ out,
                                                   int R, int C) {
  __shared__ float tl[32][33];
  const int tx = threadIdx.x, ty = threadIdx.y;
  const int c0 = blockIdx.x * 32, r0 = blockIdx.y * 32;
#pragma unroll
  for (int i = 0; i < 4; ++i)
    tl[ty + i * 8][tx] = in[(long)(r0 + ty + i * 8) * C + c0 + tx];
  __syncthreads();
#pragma unroll
  for (int i = 0; i < 4; ++i)
    out[(long)(c0 + ty + i * 8) * R + r0 + tx] = (__bf16)tl[tx][ty + i * 8];
}

// ------- build transposed+concatenated V: vt[b][kvh][hd][j], j in [0,T) -----
__global__ __launch_bounds__(256) void build_vt(const float* __restrict__ past_v,
                                                const __bf16* __restrict__ vn,
                                                __bf16* __restrict__ vt) {
  __shared__ float tl[32][33];
  const int tx = threadIdx.x, ty = threadIdx.y;
  const int j0 = blockIdx.x * 32, hd0 = blockIdx.y * 32;
  const int b = blockIdx.z >> 3, kvh = blockIdx.z & 7;
#pragma unroll
  for (int i = 0; i < 4; ++i) {
    const int j = j0 + ty + i * 8;
    float val = (j < P_)
        ? past_v[((long)((b * P_ + j) * KV_ + kvh)) * HD_ + hd0 + tx]
        : (float)vn[((long)((b * S_ + (j - P_)) * KV_ + kvh)) * HD_ + hd0 + tx];
    tl[ty + i * 8][tx] = val;
  }
  __syncthreads();
#pragma unroll
  for (int i = 0; i < 4; ++i)
    vt[((long)((b * KV_ + kvh) * HD_ + hd0 + ty + i * 8)) * T_ + j0 + tx] =
        (__bf16)tl[tx][ty + i * 8];
}

// ---------------- GEMM: C[M,N] = A[M,K] @ Bt[N,K]^T, bf16 in, fp32 acc ------
// 128x128 tile, BK=32, 256 threads (2x2 waves of 64x64), LDS stride 40 elems.
template <typename OutT>
__global__ __launch_bounds__(256, 2) void gemm_bt(const __bf16* __restrict__ A,
                                                  const __bf16* __restrict__ Bt,
                                                  OutT* __restrict__ C,
                                                  int M, int N, int K) {
  __shared__ __align__(16) __bf16 As[128][40];
  __shared__ __align__(16) __bf16 Bs[128][40];
  const int t = threadIdx.x;
  const int lane = t & 63, wave = t >> 6;
  const int wm = (wave >> 1) * 64, wn = (wave & 1) * 64;
  const int l15 = lane & 15, quad = lane >> 4;
  const long m0 = (long)blockIdx.y * 128, n0 = (long)blockIdx.x * 128;

  const int srow = t >> 2;           // 0..63
  const int sc8 = (t & 3) * 8;       // 0,8,16,24
  const __bf16* Ap = A + (m0 + srow) * K + sc8;
  const __bf16* Bp = Bt + (n0 + srow) * K + sc8;
  const long rstep = (long)64 * K;

  f32x4 acc[4][4];
#pragma unroll
  for (int i = 0; i < 4; ++i)
#pragma unroll
    for (int j = 0; j < 4; ++j)
#pragma unroll
      for (int e = 0; e < 4; ++e) acc[i][j][e] = 0.0f;

  bf16x8 ra0 = *(const bf16x8*)(Ap);
  bf16x8 ra1 = *(const bf16x8*)(Ap + rstep);
  bf16x8 rb0 = *(const bf16x8*)(Bp);
  bf16x8 rb1 = *(const bf16x8*)(Bp + rstep);

  const int nk = K >> 5;
  for (int kt = 0; kt < nk; ++kt) {
    __syncthreads();  // previous tile's readers done
    *(bf16x8*)(&As[srow][sc8]) = ra0;
    *(bf16x8*)(&As[64 + srow][sc8]) = ra1;
    *(bf16x8*)(&Bs[srow][sc8]) = rb0;
    *(bf16x8*)(&Bs[64 + srow][sc8]) = rb1;
    if (kt + 1 < nk) {  // prefetch next K-tile while computing this one
      const __bf16* An = Ap + (kt + 1) * 32;
      const __bf16* Bn = Bp + (kt + 1) * 32;
      ra0 = *(const bf16x8*)(An);
      ra1 = *(const bf16x8*)(An + rstep);
      rb0 = *(const bf16x8*)(Bn);
      rb1 = *(const bf16x8*)(Bn + rstep);
    }
    __syncthreads();  // LDS visible
    bf16x8 aF[4], bF[4];
#pragma unroll
    for (int i = 0; i < 4; ++i)
      aF[i] = *(const bf16x8*)(&As[wm + i * 16 + l15][quad * 8]);
#pragma unroll
    for (int i = 0; i < 4; ++i)
      bF[i] = *(const bf16x8*)(&Bs[wn + i * 16 + l15][quad * 8]);
#pragma unroll
    for (int i = 0; i < 4; ++i)
#pragma unroll
      for (int j = 0; j < 4; ++j)
        acc[i][j] = __builtin_amdgcn_mfma_f32_16x16x32_bf16(aF[i], bF[j],
                                                            acc[i][j], 0, 0, 0);
  }

  // epilogue: C/D layout col=lane&15, row=quad*4+reg (verified m89/m91)
#pragma unroll
  for (int i = 0; i < 4; ++i) {
    const long r0 = m0 + wm + i * 16 + quad * 4;
#pragma unroll
    for (int j = 0; j < 4; ++j) {
      const long col = n0 + wn + j * 16 + l15;
#pragma unroll
      for (int r = 0; r < 4; ++r)
        C[(r0 + r) * N + col] = (OutT)acc[i][j][r];
    }
  }
}

// ---------------- fused causal GQA flash attention ---------------------------
// grid (S/64, H, B), 256 threads. wave w owns 16 q-rows; 32-key tiles.
// Output written IN-PLACE into qio (each (s,h) slice read only by its own
// block, in the preamble, before the epilogue writes it).
__global__ __launch_bounds__(256, 2) void attn_kernel(
    __bf16* qio,                     // [B,S,H,HD] in: Q, out: attn out
    const float* __restrict__ pk,    // [B,P,KV,HD] f32
    const __bf16* __restrict__ kn,   // [B,S,KV,HD]
    const __bf16* __restrict__ vt) { // [B,KV,HD,T]
  __shared__ __align__(16) __bf16 Ks[32][136];   // [key][hd]
  __shared__ __align__(16) __bf16 Vs[128][40];   // [hd][key]
  __shared__ __align__(16) __bf16 Ps[4][16][40]; // per-wave P
  const int t = threadIdx.x;
  const int lane = t & 63, w = t >> 6;
  const int l15 = lane & 15, quad = lane >> 4;
  const int s0 = blockIdx.x * 64;
  const int h = blockIdx.y;
  const int b = blockIdx.z;
  const int kvh = h >> 2;  // G=4

  // preload Q fragments (A-operand: m=lane&15, k=quad*8+j), 4 hd-slices of 32
  bf16x8 aQ[4];
  {
    const int qrow = s0 + w * 16 + l15;
    const __bf16* qp = qio + ((long)((b * S_ + qrow) * H_ + h)) * HD_ + quad * 8;
#pragma unroll
    for (int kt = 0; kt < 4; ++kt) aQ[kt] = *(const bf16x8*)(qp + kt * 32);
  }

  f32x4 O[8];
#pragma unroll
  for (int f = 0; f < 8; ++f)
#pragma unroll
    for (int e = 0; e < 4; ++e) O[f][e] = 0.0f;
  float m_r[4], l_r[4];
#pragma unroll
  for (int r = 0; r < 4; ++r) { m_r[r] = -__builtin_inff(); l_r[r] = 0.0f; }

  const float C2 = 1.4426950408889634f * 0.08838834764831845f;  // log2e/sqrt(128)
  const int ntiles = (P_ + s0 + 63) / 32 + 1;

  for (int tile = 0; tile < ntiles; ++tile) {
    const int j0 = tile * 32;
    __syncthreads();
    // stage K tile [32 keys][128 hd] (f32 cache part converted in flight)
#pragma unroll
    for (int p = 0; p < 2; ++p) {
      const int li = p * 256 + t;
      const int key = li >> 4, ch = (li & 15) * 8;
      const int j = j0 + key;
      bf16x8 kv;
      if (j < P_) {
        const float* src = pk + ((long)((b * P_ + j) * KV_ + kvh)) * HD_ + ch;
        kv = cvt8(*(const float4*)src, *(const float4*)(src + 4));
      } else {
        kv = *(const bf16x8*)(kn + ((long)((b * S_ + (j - P_)) * KV_ + kvh)) * HD_ + ch);
      }
      *(bf16x8*)(&Ks[key][ch]) = kv;
    }
    // stage V^T tile [128 hd][32 keys] from pre-transposed vt
#pragma unroll
    for (int p = 0; p < 2; ++p) {
      const int li = p * 256 + t;
      const int hd = li >> 2, k8 = (li & 3) * 8;
      *(bf16x8*)(&Vs[hd][k8]) =
          *(const bf16x8*)(vt + ((long)((b * KV_ + kvh) * HD_ + hd)) * T_ + j0 + k8);
    }
    __syncthreads();

    // QK^T: per-wave scores [16 q][32 keys]
    f32x4 sc0, sc1;
#pragma unroll
    for (int e = 0; e < 4; ++e) { sc0[e] = 0.0f; sc1[e] = 0.0f; }
#pragma unroll
    for (int kt = 0; kt < 4; ++kt) {
      bf16x8 bk0 = *(const bf16x8*)(&Ks[l15][kt * 32 + quad * 8]);
      bf16x8 bk1 = *(const bf16x8*)(&Ks[16 + l15][kt * 32 + quad * 8]);
      sc0 = __builtin_amdgcn_mfma_f32_16x16x32_bf16(aQ[kt], bk0, sc0, 0, 0, 0);
      sc1 = __builtin_amdgcn_mfma_f32_16x16x32_bf16(aQ[kt], bk1, sc1, 0, 0, 0);
    }

    // online softmax (C layout: key=lane&15(+16), q=quad*4+r)
    float alpha[4];
#pragma unroll
    for (int r = 0; r < 4; ++r) {
      const int bound = P_ + s0 + w * 16 + quad * 4 + r;  // max allowed key
      float v0 = (j0 + l15 <= bound) ? sc0[r] : -__builtin_inff();
      float v1 = (j0 + 16 + l15 <= bound) ? sc1[r] : -__builtin_inff();
      float mt = fmaxf(v0, v1);
      mt = fmaxf(mt, __shfl_xor(mt, 1));
      mt = fmaxf(mt, __shfl_xor(mt, 2));
      mt = fmaxf(mt, __shfl_xor(mt, 4));
      mt = fmaxf(mt, __shfl_xor(mt, 8));
      const float mn = fmaxf(m_r[r], mt);
      const float p0 = exp2f((v0 - mn) * C2);
      const float p1 = exp2f((v1 - mn) * C2);
      float rs = p0 + p1;
      rs += __shfl_xor(rs, 1);
      rs += __shfl_xor(rs, 2);
      rs += __shfl_xor(rs, 4);
      rs += __shfl_xor(rs, 8);
      alpha[r] = exp2f((m_r[r] - mn) * C2);
      m_r[r] = mn;
      l_r[r] = l_r[r] * alpha[r] + rs;
      Ps[w][quad * 4 + r][l15] = (__bf16)p0;
      Ps[w][quad * 4 + r][16 + l15] = (__bf16)p1;
    }
#pragma unroll
    for (int f = 0; f < 8; ++f)
#pragma unroll
      for (int r = 0; r < 4; ++r) O[f][r] *= alpha[r];

    __syncthreads();  // P visible (conservative: removes DS-ordering assumption)

    // PV: O[16 q][128 hd] += P[16][32] @ V[32][128]
    bf16x8 aP = *(const bf16x8*)(&Ps[w][l15][quad * 8]);
#pragma unroll
    for (int f = 0; f < 8; ++f) {
      bf16x8 bV = *(const bf16x8*)(&Vs[f * 16 + l15][quad * 8]);
      O[f] = __builtin_amdgcn_mfma_f32_16x16x32_bf16(aP, bV, O[f], 0, 0, 0);
    }
  }

  // epilogue: normalize by l, store in-place
#pragma unroll
  for (int r = 0; r < 4; ++r) {
    const float inv = 1.0f / l_r[r];
    const long row = (long)((b * S_ + s0 + w * 16 + quad * 4 + r) * H_ + h);
#pragma unroll
    for (int f = 0; f < 8; ++f)
      qio[row * HD_ + f * 16 + l15] = (__bf16)(O[f][r] * inv);
  }
}

extern "C" void kernel_launch(void* const* d_in, const int* in_sizes, int n_in,
                              void* d_out, int out_size, void* d_ws, size_t ws_size,
                              hipStream_t stream) {
  const float* x  = (const float*)d_in[0];
  const float* pk = (const float*)d_in[1];
  const float* pv = (const float*)d_in[2];
  const float* Wq = (const float*)d_in[3];
  const float* Wk = (const float*)d_in[4];
  const float* Wv = (const float*)d_in[5];
  const float* Wo = (const float*)d_in[6];
  float* out = (float*)d_out;
  char* ws = (char*)d_ws;
  // workspace layout, 117,440,512 B total (vt aliases dead xb)
  __bf16* wt = (__bf16*)(ws);                       // 33,554,432 B  W^T bf16
  __bf16* q  = (__bf16*)(ws + (size_t)33554432);    // 33,554,432 B  [B,S,H,HD]
  __bf16* kn = (__bf16*)(ws + (size_t)67108864);    //  8,388,608 B  [B,S,KV,HD]
  __bf16* vn = (__bf16*)(ws + (size_t)75497472);    //  8,388,608 B  [B,S,KV,HD]
  __bf16* xb = (__bf16*)(ws + (size_t)83886080);    // 33,554,432 B  x bf16
  __bf16* vt = (__bf16*)(ws + (size_t)83886080);    // 12,582,912 B  [B,KV,HD,T] (after xb dead)

  dim3 tb(32, 8);
  // x -> bf16
  cvt_f32_bf16<<<8192, 256, 0, stream>>>(x, xb);
  // q = x @ Wq
  transpose2d<<<dim3(128, 128), tb, 0, stream>>>(Wq, wt, D_, D_);
  gemm_bt<__bf16><<<dim3(32, 32), 256, 0, stream>>>(xb, wt, q, B_ * S_, D_, D_);
  // k_new = x @ Wk
  transpose2d<<<dim3(32, 128), tb, 0, stream>>>(Wk, wt, D_, KV_ * HD_);
  gemm_bt<__bf16><<<dim3(8, 32), 256, 0, stream>>>(xb, wt, kn, B_ * S_, KV_ * HD_, D_);
  // v_new = x @ Wv  (last use of xb)
  transpose2d<<<dim3(32, 128), tb, 0, stream>>>(Wv, wt, D_, KV_ * HD_);
  gemm_bt<__bf16><<<dim3(8, 32), 256, 0, stream>>>(xb, wt, vn, B_ * S_, KV_ * HD_, D_);
  // V^T (concat past+new), overwrites xb region
  build_vt<<<dim3(96, 4, 16), tb, 0, stream>>>(pv, vn, vt);
  // attention (in-place on q)
  attn_kernel<<<dim3(32, 32, 2), 256, 0, stream>>>(q, pk, kn, vt);
  // out = attn @ Wo  (f32 output)
  transpose2d<<<dim3(128, 128), tb, 0, stream>>>(Wo, wt, D_, D_);
  gemm_bt<float><<<dim3(32, 32), 256, 0, stream>>>(q, wt, out, B_ * S_, D_, D_);
}

// Round 3
// 1209.266 us; speedup vs baseline: 1.0821x; 1.0821x over previous
//
#include <hip/hip_runtime.h>

typedef __bf16 bf16x8 __attribute__((ext_vector_type(8)));
typedef float f32x4 __attribute__((ext_vector_type(4)));
using gptr_t = const __attribute__((address_space(1))) void*;
using sptr_t = __attribute__((address_space(3))) void*;

#define B_ 2
#define S_ 2048
#define D_ 4096
#define H_ 32
#define KV_ 8
#define G_ 4
#define HD_ 128
#define P_ 1024
#define T_ 3072

__device__ inline bf16x8 cvt8(const float4 a, const float4 b) {
  bf16x8 r;
  r[0] = (__bf16)a.x; r[1] = (__bf16)a.y; r[2] = (__bf16)a.z; r[3] = (__bf16)a.w;
  r[4] = (__bf16)b.x; r[5] = (__bf16)b.y; r[6] = (__bf16)b.z; r[7] = (__bf16)b.w;
  return r;
}

// ---------------- f32 -> bf16 elementwise convert (8 elems/thread) ----------
__global__ __launch_bounds__(256) void cvt_f32_bf16(const float* __restrict__ in,
                                                    __bf16* __restrict__ out) {
  const long i = ((long)blockIdx.x * 256 + threadIdx.x) * 8;
  float4 a = *(const float4*)(in + i);
  float4 b = *(const float4*)(in + i + 4);
  *(bf16x8*)(out + i) = cvt8(a, b);
}

// ------------- transpose: out[c][r] = bf16(in[r][c]), in f32 R x C ----------
__global__ __launch_bounds__(256) void transpose2d(const float* __restrict__ in,
                                                   __bf16* __restrict__ out,
                                                   int R, int C) {
  __shared__ float tl[32][33];
  const int tx = threadIdx.x, ty = threadIdx.y;
  const int c0 = blockIdx.x * 32, r0 = blockIdx.y * 32;
#pragma unroll
  for (int i = 0; i < 4; ++i)
    tl[ty + i * 8][tx] = in[(long)(r0 + ty + i * 8) * C + c0 + tx];
  __syncthreads();
#pragma unroll
  for (int i = 0; i < 4; ++i)
    out[(long)(c0 + ty + i * 8) * R + r0 + tx] = (__bf16)tl[tx][ty + i * 8];
}

// ------- build transposed+concatenated V: vt[b][kvh][hd][j], j in [0,T) -----
__global__ __launch_bounds__(256) void build_vt(const float* __restrict__ past_v,
                                                const __bf16* __restrict__ vn,
                                                __bf16* __restrict__ vt) {
  __shared__ float tl[32][33];
  const int tx = threadIdx.x, ty = threadIdx.y;
  const int j0 = blockIdx.x * 32, hd0 = blockIdx.y * 32;
  const int b = blockIdx.z >> 3, kvh = blockIdx.z & 7;
#pragma unroll
  for (int i = 0; i < 4; ++i) {
    const int j = j0 + ty + i * 8;
    float val = (j < P_)
        ? past_v[((long)((b * P_ + j) * KV_ + kvh)) * HD_ + hd0 + tx]
        : (float)vn[((long)((b * S_ + (j - P_)) * KV_ + kvh)) * HD_ + hd0 + tx];
    tl[ty + i * 8][tx] = val;
  }
  __syncthreads();
#pragma unroll
  for (int i = 0; i < 4; ++i)
    vt[((long)((b * KV_ + kvh) * HD_ + hd0 + ty + i * 8)) * T_ + j0 + tx] =
        (__bf16)tl[tx][ty + i * 8];
}

// ---------------- GEMM (m97 structure): C[M,N] = A[M,K] @ Bt[N,K]^T ---------
// 128x128 tile, BK=32, global_load_lds width=16, unpadded LDS [128][32].
template <typename OutT>
__global__ __launch_bounds__(256, 3) void gemm_bt(const __bf16* __restrict__ A,
                                                  const __bf16* __restrict__ Bt,
                                                  OutT* __restrict__ C,
                                                  int M, int N, int K) {
  __shared__ __align__(16) __bf16 As[128][32];
  __shared__ __align__(16) __bf16 Bs[128][32];
  const int t = threadIdx.x;
  const int lane = t & 63, wave = t >> 6;
  const int wm = (wave >> 1) * 64, wn = (wave & 1) * 64;
  const int l15 = lane & 15, quad = lane >> 4;
  const long m0 = (long)blockIdx.y * 128, n0 = (long)blockIdx.x * 128;

  // staging: wave w covers rows w*32..w*32+31 (2 calls of 16 rows);
  // lane l -> row +(l>>2), col (l&3)*8  == LDS base + l*16B (wave-uniform base)
  const int srow = wave * 32 + (lane >> 2);
  const int scol = (lane & 3) * 8;
  const __bf16* Ap = A + (m0 + srow) * K + scol;
  const __bf16* Bp = Bt + (n0 + srow) * K + scol;
  const long rstep = 16L * K;
  sptr_t ldsA0 = (sptr_t)&As[wave * 32][0];
  sptr_t ldsA1 = (sptr_t)&As[wave * 32 + 16][0];
  sptr_t ldsB0 = (sptr_t)&Bs[wave * 32][0];
  sptr_t ldsB1 = (sptr_t)&Bs[wave * 32 + 16][0];

  f32x4 acc[4][4];
#pragma unroll
  for (int i = 0; i < 4; ++i)
#pragma unroll
    for (int j = 0; j < 4; ++j)
#pragma unroll
      for (int e = 0; e < 4; ++e) acc[i][j][e] = 0.0f;

  const int nk = K >> 5;
  for (int kt = 0; kt < nk; ++kt) {
    __syncthreads();  // prior tile's frag reads done
    __builtin_amdgcn_global_load_lds((gptr_t)(Ap + kt * 32), ldsA0, 16, 0, 0);
    __builtin_amdgcn_global_load_lds((gptr_t)(Ap + rstep + kt * 32), ldsA1, 16, 0, 0);
    __builtin_amdgcn_global_load_lds((gptr_t)(Bp + kt * 32), ldsB0, 16, 0, 0);
    __builtin_amdgcn_global_load_lds((gptr_t)(Bp + rstep + kt * 32), ldsB1, 16, 0, 0);
    __syncthreads();  // vmcnt(0) drain + barrier: LDS tile ready
    bf16x8 aF[4], bF[4];
#pragma unroll
    for (int i = 0; i < 4; ++i)
      aF[i] = *(const bf16x8*)(&As[wm + i * 16 + l15][quad * 8]);
#pragma unroll
    for (int i = 0; i < 4; ++i)
      bF[i] = *(const bf16x8*)(&Bs[wn + i * 16 + l15][quad * 8]);
#pragma unroll
    for (int i = 0; i < 4; ++i)
#pragma unroll
      for (int j = 0; j < 4; ++j)
        acc[i][j] = __builtin_amdgcn_mfma_f32_16x16x32_bf16(aF[i], bF[j],
                                                            acc[i][j], 0, 0, 0);
  }

  // epilogue: C/D layout col=lane&15, row=quad*4+reg
#pragma unroll
  for (int i = 0; i < 4; ++i) {
    const long r0 = m0 + wm + i * 16 + quad * 4;
#pragma unroll
    for (int j = 0; j < 4; ++j) {
      const long col = n0 + wn + j * 16 + l15;
#pragma unroll
      for (int r = 0; r < 4; ++r)
        C[(r0 + r) * N + col] = (OutT)acc[i][j][r];
    }
  }
}

// ---------------- fused causal GQA flash attention ---------------------------
// grid (S/128, H, B), 256 threads. Block = 128 q-rows of one head; wave owns
// 32 rows (2 m-frags). 64-key tiles. Row-sums via P@ones MFMA (no sum-shfl).
__global__ __launch_bounds__(256, 2) void attn_kernel(
    __bf16* qio,                     // [B,S,H,HD] in: Q, out: attn out (in-place)
    const float* __restrict__ pk,    // [B,P,KV,HD] f32
    const __bf16* __restrict__ kn,   // [B,S,KV,HD]
    const __bf16* __restrict__ vt) { // [B,KV,HD,T]
  __shared__ __align__(16) __bf16 Ks[64][136];    // [key][hd]   17408 B
  __shared__ __align__(16) __bf16 Vs[128][72];    // [hd][key]   18432 B
  __shared__ __align__(16) __bf16 Ps[4][32][72];  // per-wave P  18432 B
  const int t = threadIdx.x;
  const int lane = t & 63, w = t >> 6;
  const int l15 = lane & 15, quad = lane >> 4;
  const int s0 = blockIdx.x * 128;
  const int h = blockIdx.y, b = blockIdx.z;
  const int kvh = h >> 2;  // G=4

  // Q fragments: aQ[mi][kt], A-layout m=lane&15, k=quad*8+j
  bf16x8 aQ[2][4];
#pragma unroll
  for (int mi = 0; mi < 2; ++mi) {
    const int qrow = s0 + w * 32 + mi * 16 + l15;
    const __bf16* qp = qio + ((long)((b * S_ + qrow) * H_ + h)) * HD_ + quad * 8;
#pragma unroll
    for (int kt = 0; kt < 4; ++kt) aQ[mi][kt] = *(const bf16x8*)(qp + kt * 32);
  }

  f32x4 O[2][8];
#pragma unroll
  for (int mi = 0; mi < 2; ++mi)
#pragma unroll
    for (int f = 0; f < 8; ++f)
#pragma unroll
      for (int e = 0; e < 4; ++e) O[mi][f][e] = 0.0f;
  float m_r[2][4], l_r[2][4];
#pragma unroll
  for (int mi = 0; mi < 2; ++mi)
#pragma unroll
    for (int r = 0; r < 4; ++r) { m_r[mi][r] = -__builtin_inff(); l_r[mi][r] = 0.0f; }

  bf16x8 ones;
#pragma unroll
  for (int e = 0; e < 8; ++e) ones[e] = (__bf16)1.0f;

  const float C2 = 1.4426950408889634f * 0.08838834764831845f;  // log2e/sqrt(128)
  const int ntiles = (P_ + s0 + 128) / 64;
  const int wave_last_key = P_ + s0 + w * 32 + 31;   // max key this wave needs
  const int wave_min_bound = P_ + s0 + w * 32;       // min bound over wave rows

  for (int tile = 0; tile < ntiles; ++tile) {
    const int j0 = tile * 64;
    __syncthreads();
    // stage K tile [64 keys][128 hd] (f32 cache part converted in flight)
#pragma unroll
    for (int p = 0; p < 4; ++p) {
      const int li = p * 256 + t;
      const int key = li >> 4, ch = (li & 15) * 8;
      const int j = j0 + key;
      bf16x8 kv;
      if (j < P_) {
        const float* src = pk + ((long)((b * P_ + j) * KV_ + kvh)) * HD_ + ch;
        kv = cvt8(*(const float4*)src, *(const float4*)(src + 4));
      } else {
        kv = *(const bf16x8*)(kn + ((long)((b * S_ + (j - P_)) * KV_ + kvh)) * HD_ + ch);
      }
      *(bf16x8*)(&Ks[key][ch]) = kv;
    }
    // stage V^T tile [128 hd][64 keys]
#pragma unroll
    for (int p = 0; p < 4; ++p) {
      const int li = p * 256 + t;
      const int hd = li >> 3, k8 = (li & 7) * 8;
      *(bf16x8*)(&Vs[hd][k8]) =
          *(const bf16x8*)(vt + ((long)((b * KV_ + kvh) * HD_ + hd)) * T_ + j0 + k8);
    }
    __syncthreads();

    if (j0 > wave_last_key) continue;  // trailing tile not needed by this wave

    // QK^T: sc[mi][kf] = scores [32 q][64 keys]; each bk feeds 2 MFMAs
    f32x4 sc[2][4];
#pragma unroll
    for (int mi = 0; mi < 2; ++mi)
#pragma unroll
      for (int kf = 0; kf < 4; ++kf)
#pragma unroll
        for (int e = 0; e < 4; ++e) sc[mi][kf][e] = 0.0f;
#pragma unroll
    for (int kf = 0; kf < 4; ++kf) {
#pragma unroll
      for (int kt = 0; kt < 4; ++kt) {
        bf16x8 bk = *(const bf16x8*)(&Ks[kf * 16 + l15][kt * 32 + quad * 8]);
        sc[0][kf] = __builtin_amdgcn_mfma_f32_16x16x32_bf16(aQ[0][kt], bk, sc[0][kf], 0, 0, 0);
        sc[1][kf] = __builtin_amdgcn_mfma_f32_16x16x32_bf16(aQ[1][kt], bk, sc[1][kf], 0, 0, 0);
      }
    }

    // online softmax (C layout: key=kf*16+(lane&15), q-row=quad*4+r)
    const bool need_mask = (j0 + 63 > wave_min_bound);  // wave-uniform branch
    float alpha[2][4];
#pragma unroll
    for (int mi = 0; mi < 2; ++mi) {
#pragma unroll
      for (int r = 0; r < 4; ++r) {
        float v0 = sc[mi][0][r], v1 = sc[mi][1][r];
        float v2 = sc[mi][2][r], v3 = sc[mi][3][r];
        if (need_mask) {
          const int bound = P_ + s0 + w * 32 + mi * 16 + quad * 4 + r;
          v0 = (j0 + l15 <= bound) ? v0 : -__builtin_inff();
          v1 = (j0 + 16 + l15 <= bound) ? v1 : -__builtin_inff();
          v2 = (j0 + 32 + l15 <= bound) ? v2 : -__builtin_inff();
          v3 = (j0 + 48 + l15 <= bound) ? v3 : -__builtin_inff();
        }
        float mt = fmaxf(fmaxf(v0, v1), fmaxf(v2, v3));
        mt = fmaxf(mt, __shfl_xor(mt, 1));
        mt = fmaxf(mt, __shfl_xor(mt, 2));
        mt = fmaxf(mt, __shfl_xor(mt, 4));
        mt = fmaxf(mt, __shfl_xor(mt, 8));
        const float mn = fmaxf(m_r[mi][r], mt);
        const float p0 = exp2f((v0 - mn) * C2);
        const float p1 = exp2f((v1 - mn) * C2);
        const float p2 = exp2f((v2 - mn) * C2);
        const float p3 = exp2f((v3 - mn) * C2);
        alpha[mi][r] = exp2f((m_r[mi][r] - mn) * C2);
        m_r[mi][r] = mn;
        const int row = mi * 16 + quad * 4 + r;
        Ps[w][row][l15] = (__bf16)p0;
        Ps[w][row][16 + l15] = (__bf16)p1;
        Ps[w][row][32 + l15] = (__bf16)p2;
        Ps[w][row][48 + l15] = (__bf16)p3;
      }
    }
    // rescale O
#pragma unroll
    for (int mi = 0; mi < 2; ++mi)
#pragma unroll
      for (int f = 0; f < 8; ++f)
#pragma unroll
        for (int r = 0; r < 4; ++r) O[mi][f][r] *= alpha[mi][r];

    // PV + row sums via MFMA (each bV feeds 2 MFMAs)
    f32x4 sums[2];
#pragma unroll
    for (int e = 0; e < 4; ++e) { sums[0][e] = 0.0f; sums[1][e] = 0.0f; }
#pragma unroll
    for (int kf2 = 0; kf2 < 2; ++kf2) {
      bf16x8 aP0 = *(const bf16x8*)(&Ps[w][l15][kf2 * 32 + quad * 8]);
      bf16x8 aP1 = *(const bf16x8*)(&Ps[w][16 + l15][kf2 * 32 + quad * 8]);
      sums[0] = __builtin_amdgcn_mfma_f32_16x16x32_bf16(aP0, ones, sums[0], 0, 0, 0);
      sums[1] = __builtin_amdgcn_mfma_f32_16x16x32_bf16(aP1, ones, sums[1], 0, 0, 0);
#pragma unroll
      for (int f = 0; f < 8; ++f) {
        bf16x8 bV = *(const bf16x8*)(&Vs[f * 16 + l15][kf2 * 32 + quad * 8]);
        O[0][f] = __builtin_amdgcn_mfma_f32_16x16x32_bf16(aP0, bV, O[0][f], 0, 0, 0);
        O[1][f] = __builtin_amdgcn_mfma_f32_16x16x32_bf16(aP1, bV, O[1][f], 0, 0, 0);
      }
    }
#pragma unroll
    for (int mi = 0; mi < 2; ++mi)
#pragma unroll
      for (int r = 0; r < 4; ++r)
        l_r[mi][r] = l_r[mi][r] * alpha[mi][r] + sums[mi][r];
  }

  // epilogue: normalize, store in-place
#pragma unroll
  for (int mi = 0; mi < 2; ++mi) {
#pragma unroll
    for (int r = 0; r < 4; ++r) {
      const float inv = 1.0f / l_r[mi][r];
      const long row =
          (long)((b * S_ + s0 + w * 32 + mi * 16 + quad * 4 + r) * H_ + h);
#pragma unroll
      for (int f = 0; f < 8; ++f)
        qio[row * HD_ + f * 16 + l15] = (__bf16)(O[mi][f][r] * inv);
    }
  }
}

extern "C" void kernel_launch(void* const* d_in, const int* in_sizes, int n_in,
                              void* d_out, int out_size, void* d_ws, size_t ws_size,
                              hipStream_t stream) {
  const float* x  = (const float*)d_in[0];
  const float* pk = (const float*)d_in[1];
  const float* pv = (const float*)d_in[2];
  const float* Wq = (const float*)d_in[3];
  const float* Wk = (const float*)d_in[4];
  const float* Wv = (const float*)d_in[5];
  const float* Wo = (const float*)d_in[6];
  float* out = (float*)d_out;
  char* ws = (char*)d_ws;
  __bf16* wt = (__bf16*)(ws);                       // 33,554,432 B  W^T bf16
  __bf16* q  = (__bf16*)(ws + (size_t)33554432);    // 33,554,432 B  [B,S,H,HD]
  __bf16* kn = (__bf16*)(ws + (size_t)67108864);    //  8,388,608 B  [B,S,KV,HD]
  __bf16* vn = (__bf16*)(ws + (size_t)75497472);    //  8,388,608 B  [B,S,KV,HD]
  __bf16* xb = (__bf16*)(ws + (size_t)83886080);    // 33,554,432 B  x bf16
  __bf16* vt = (__bf16*)(ws + (size_t)83886080);    // 12,582,912 B  (aliases dead xb)

  dim3 tb(32, 8);
  cvt_f32_bf16<<<8192, 256, 0, stream>>>(x, xb);
  // q = x @ Wq
  transpose2d<<<dim3(128, 128), tb, 0, stream>>>(Wq, wt, D_, D_);
  gemm_bt<__bf16><<<dim3(32, 32), 256, 0, stream>>>(xb, wt, q, B_ * S_, D_, D_);
  // k_new = x @ Wk
  transpose2d<<<dim3(32, 128), tb, 0, stream>>>(Wk, wt, D_, KV_ * HD_);
  gemm_bt<__bf16><<<dim3(8, 32), 256, 0, stream>>>(xb, wt, kn, B_ * S_, KV_ * HD_, D_);
  // v_new = x @ Wv  (last use of xb)
  transpose2d<<<dim3(32, 128), tb, 0, stream>>>(Wv, wt, D_, KV_ * HD_);
  gemm_bt<__bf16><<<dim3(8, 32), 256, 0, stream>>>(xb, wt, vn, B_ * S_, KV_ * HD_, D_);
  // V^T (concat past+new), overwrites xb region
  build_vt<<<dim3(96, 4, 16), tb, 0, stream>>>(pv, vn, vt);
  // attention (in-place on q)
  attn_kernel<<<dim3(16, 32, 2), 256, 0, stream>>>(q, pk, kn, vt);
  // out = attn @ Wo  (f32 output)
  transpose2d<<<dim3(128, 128), tb, 0, stream>>>(Wo, wt, D_, D_);
  gemm_bt<float><<<dim3(32, 32), 256, 0, stream>>>(q, wt, out, B_ * S_, D_, D_);
}